// Round 2
// baseline (644.967 us; speedup 1.0000x reference)
//
#include <hip/hip_runtime.h>

// Problem constants
#define B_ 2
#define S_ 5
#define C_ 256
#define H_ 192
#define W_ 192
#define K_ 7
#define NH_ 28
#define NW_ 28
#define NSITE_ 784   // NH_*NW_
#define HID_ 16

// g layout: [b][s][c][n*28+m]  (contiguous 784-float block per (b,s,c))
// wt layout: [b][s][site]      (site = n*28+m)

// ---------------------------------------------------------------------------
// Kernel 1: window means. One block per (b,s,c) plane; 256 threads (4 waves).
// Wave w owns bands t = w, w+4, ..., w+24 (7 each). Lanes 0..47 column-sum the
// 7-row band with float4 loads; lanes 0..27 reduce groups of 7 columns.
// Writes 784 contiguous floats per block (no write amplification).
// ---------------------------------------------------------------------------
__global__ __launch_bounds__(256) void k_means(const float* __restrict__ x,
                                               float* __restrict__ g) {
    int idx = blockIdx.x;                       // (b*S + s)*C + c
    const float* plane = x + (size_t)idx * (H_ * W_);
    float* gout = g + (size_t)idx * NSITE_;
    __shared__ float colsum[4][W_];
    int w = threadIdx.x >> 6;
    int lane = threadIdx.x & 63;
    for (int t = w; t < NH_; t += 4) {          // exactly 7 iterations per wave
        if (lane < 48) {
            const float* rp = plane + (7 * t) * W_ + 4 * lane;
            float4 cs = make_float4(0.f, 0.f, 0.f, 0.f);
            if (7 * t + 7 <= H_) {              // full band (t < 27)
#pragma unroll
                for (int r = 0; r < 7; ++r) {
                    float4 v = *(const float4*)(rp + r * W_);
                    cs.x += v.x; cs.y += v.y; cs.z += v.z; cs.w += v.w;
                }
            } else {                            // band 27: rows 189..191 only
#pragma unroll
                for (int r = 0; r < 3; ++r) {
                    float4 v = *(const float4*)(rp + r * W_);
                    cs.x += v.x; cs.y += v.y; cs.z += v.z; cs.w += v.w;
                }
            }
            *(float4*)&colsum[w][4 * lane] = cs;
        }
        __syncthreads();
        if (lane < NW_) {
            int c0 = lane * 7;
            float ssum = 0.f;
#pragma unroll
            for (int d = 0; d < 7; ++d) {
                int cc = c0 + d;
                if (cc < W_) ssum += colsum[w][cc];   // pad cols contribute 0
            }
            gout[t * NW_ + lane] = ssum * (1.0f / 49.0f);
        }
        __syncthreads();
    }
}

// ---------------------------------------------------------------------------
// Kernel 2: tiny MLP over C + softmax over S. Grid = B * 13 chunks of 64
// sites; 320 threads = 5 waves, wave s handles slice s, lane = site.
// g reads are lane-coalesced (site is the fastest axis of g).
// ---------------------------------------------------------------------------
__global__ __launch_bounds__(320) void k_mlp(const float* __restrict__ g,
                                             const float* __restrict__ w1,
                                             const float* __restrict__ b1,
                                             const float* __restrict__ w2,
                                             const float* __restrict__ b2,
                                             const float* __restrict__ sl,
                                             float* __restrict__ wt) {
    int b = blockIdx.x / 13;
    int chunk = blockIdx.x % 13;
    int s = threadIdx.x >> 6;
    int lane = threadIdx.x & 63;
    int site = chunk * 64 + lane;
    bool valid = site < NSITE_;
    int site_c = valid ? site : (NSITE_ - 1);
    const float* gp = g + ((size_t)(b * S_ + s) * C_) * NSITE_ + site_c;
    float h[HID_];
#pragma unroll
    for (int j = 0; j < HID_; ++j) h[j] = 0.f;
#pragma unroll 4
    for (int c = 0; c < C_; ++c) {
        float gv = gp[(size_t)c * NSITE_];
#pragma unroll
        for (int j = 0; j < HID_; ++j) h[j] = fmaf(w1[j * C_ + c], gv, h[j]);
    }
    float logit = b2[0] + sl[s];
#pragma unroll
    for (int j = 0; j < HID_; ++j) {
        float hv = h[j] + b1[j];
        hv = hv > 0.f ? hv : 0.f;
        logit = fmaf(w2[j], hv, logit);
    }
    __shared__ float lg[S_][64];
    lg[s][lane] = logit;
    __syncthreads();
    if (valid) {
        float l0 = lg[0][lane], l1 = lg[1][lane], l2 = lg[2][lane],
              l3 = lg[3][lane], l4 = lg[4][lane];
        float mx = fmaxf(fmaxf(fmaxf(l0, l1), fmaxf(l2, l3)), l4);
        float e0 = expf(l0 - mx), e1 = expf(l1 - mx), e2 = expf(l2 - mx),
              e3 = expf(l3 - mx), e4 = expf(l4 - mx);
        float inv = 1.f / (e0 + e1 + e2 + e3 + e4);
        float es = (s == 0) ? e0 : (s == 1) ? e1 : (s == 2) ? e2
                 : (s == 3) ? e3 : e4;
        wt[(b * S_ + s) * NSITE_ + site] = es * inv;
    }
}

// ---------------------------------------------------------------------------
// Kernel 3: weighted gather. One block per (b,c,n): stage 5 slices x 7
// contiguous source rows (rows 7n..7n+6, clipped) in LDS with float4 loads,
// then write the 7 output rows i = 28*kh + n (i<192) coalesced.
// ---------------------------------------------------------------------------
__global__ __launch_bounds__(448) void k_out(const float* __restrict__ x,
                                             const float* __restrict__ wt,
                                             float* __restrict__ out) {
    int idx = blockIdx.x;
    int n = idx % NH_; idx /= NH_;
    int c = idx % C_;  idx /= C_;
    int b = idx;
    __shared__ float srow[S_][7 * W_];      // 5 x 1344 floats = 26.25 KB
    __shared__ float wrow[S_][NW_];
    int tid = threadIdx.x;
    int r0 = 7 * n;
    int nrows = (H_ - r0 < 7) ? (H_ - r0) : 7;   // 7, or 3 for n=27
    int nf4 = nrows * (W_ / 4);                  // valid float4s per slice
    // flat staging: 5 * 336 = 1680 float4 over 448 threads (3.75 iters)
    for (int t = tid; t < S_ * 336; t += 448) {
        int s = t / 336, tt = t - s * 336;
        const float4* src = (const float4*)(x +
            (((size_t)((b * S_ + s) * C_ + c)) * H_ + r0) * W_);
        ((float4*)&srow[s][0])[tt] =
            (tt < nf4) ? src[tt] : make_float4(0.f, 0.f, 0.f, 0.f);
    }
    if (tid < S_ * NW_) {
        int s = tid / NW_, m = tid % NW_;
        wrow[s][m] = wt[(b * S_ + s) * NSITE_ + n * NW_ + m];
    }
    __syncthreads();
    // 1344 outputs: o = kh*192 + j, output row i = 28*kh + n
#pragma unroll
    for (int it = 0; it < 3; ++it) {
        int o = it * 448 + tid;
        int kh = o / W_, j = o - kh * W_;
        int i = NH_ * kh + n;
        if (i >= H_) continue;
        int m = j % NW_, kw = j / NW_;
        int col = m * K_ + kw;                   // may be >=192 (pad col)
        float val = 0.f;
        if (col < W_) {
            const float* sp = &srow[0][kh * W_ + col];
#pragma unroll
            for (int s = 0; s < S_; ++s)
                val = fmaf(wrow[s][m], srow[s][kh * W_ + col], val);
        }
        out[(((size_t)(b * C_ + c)) * H_ + i) * (size_t)W_ + j] = val;
    }
}

extern "C" void kernel_launch(void* const* d_in, const int* in_sizes, int n_in,
                              void* d_out, int out_size, void* d_ws, size_t ws_size,
                              hipStream_t stream) {
    const float* x  = (const float*)d_in[0];
    const float* w1 = (const float*)d_in[1];
    const float* b1 = (const float*)d_in[2];
    const float* w2 = (const float*)d_in[3];
    const float* b2 = (const float*)d_in[4];
    const float* sl = (const float*)d_in[5];
    float* out = (float*)d_out;

    float* g  = (float*)d_ws;                              // B*S*C*784 = 8.03 MB
    float* wt = g + (size_t)B_ * S_ * C_ * NSITE_;         // B*S*784 floats

    k_means<<<B_ * S_ * C_, 256, 0, stream>>>(x, g);
    k_mlp<<<B_ * 13, 320, 0, stream>>>(g, w1, b1, w2, b2, sl, wt);
    k_out<<<B_ * C_ * NH_, 448, 0, stream>>>(x, wt, out);
}